// Round 15
// baseline (222.711 us; speedup 1.0000x reference)
//
#include <hip/hip_runtime.h>
#include <stdint.h>
#include <stddef.h>
#include <math.h>

// ---------- types ----------
typedef __attribute__((ext_vector_type(8))) short bf16x8;   // 8 bf16 = 4 VGPRs
typedef __attribute__((ext_vector_type(4))) short short4v;
typedef __attribute__((ext_vector_type(4))) float f32x4;

// bf16 round-to-nearest-even from fp32
__device__ __forceinline__ short f2bf(float f) {
  union { float f; uint32_t u; } x; x.f = f;
  return (short)((x.u + 0x7fffu + ((x.u >> 16) & 1u)) >> 16);
}
__device__ __forceinline__ float bf2f(short s) {
  union { uint32_t u; float f; } x; x.u = ((uint32_t)(uint16_t)s) << 16;
  return x.f;
}
// pack 2 fp32 -> 2 bf16 (RTNE) in one instruction
__device__ __forceinline__ uint32_t cvt_pk_bf16(float a, float b) {
  uint32_t r;
  asm("v_cvt_pk_bf16_f32 %0, %1, %2" : "=v"(r) : "v"(a), "v"(b));
  return r;
}

// async global->LDS, 16B per lane; lds base must be wave-uniform
__device__ __forceinline__ void gload_lds16(const void* g, void* lds) {
  __builtin_amdgcn_global_load_lds(
      (const __attribute__((address_space(1))) void*)g,
      (__attribute__((address_space(3))) void*)lds, 16, 0, 0);
}

// ---------- fused prep: X cast (blocks 0..2047) + W transpose-cast (2048..6143)
// cast block 0 also zeroes Cvs (stream-ordered before gemm_qkv's atomics).
__global__ __launch_bounds__(256) void prep(const float* __restrict__ X,
                                            const float* __restrict__ Wq,
                                            const float* __restrict__ Wk,
                                            const float* __restrict__ Wv,
                                            const float* __restrict__ Wo,
                                            short* __restrict__ Xbf,
                                            short* __restrict__ WcatT,
                                            short* __restrict__ WoT,
                                            float* __restrict__ Cvs) {
  __shared__ float tl[32][33];
  int bid = blockIdx.x;
  if (bid < 2048) {
    if (bid == 0) {
      int c4 = threadIdx.x * 4;
      Cvs[c4] = 0.f; Cvs[c4 + 1] = 0.f; Cvs[c4 + 2] = 0.f; Cvs[c4 + 3] = 0.f;
    }
    int i4 = (bid * 256 + threadIdx.x) * 4;
    float4 v = *(const float4*)&X[i4];
    short4v r = { f2bf(v.x), f2bf(v.y), f2bf(v.z), f2bf(v.w) };
    *(short4v*)&Xbf[i4] = r;
  } else {
    int wb = bid - 2048;           // 0..4095
    int z = wb >> 10;              // matrix 0..3
    int bx = (wb >> 5) & 31;       // k-tile
    int by = wb & 31;              // n-tile
    const float* src = (z == 0) ? Wq : (z == 1) ? Wk : (z == 2) ? Wv : Wo;
    short* dst = (z == 3) ? WoT : WcatT + (size_t)z * 1024 * 1024;
    int tx = threadIdx.x & 31, ty = threadIdx.x >> 5;  // 32 x 8
    int kk0 = bx * 32;   // src rows (k)
    int nn0 = by * 32;   // src cols (n)
#pragma unroll
    for (int j = 0; j < 4; j++)
      tl[ty + j * 8][tx] = src[(size_t)(kk0 + ty + j * 8) * 1024 + nn0 + tx];
    __syncthreads();
#pragma unroll
    for (int j = 0; j < 4; j++)
      dst[(size_t)(nn0 + ty + j * 8) * 1024 + kk0 + tx] = f2bf(tl[tx][ty + j * 8]);
  }
}

// gather-reduce over 32-row chunk partials, XCD-pinned slot map (round 6).
// chunk (c, j): k-groups {2c, 2c+1} (full, j >= 4c+2) or {2c} (single,
// j in {4c, 4c+1}).  Forward map (see attn_kernel): XCD x = b&7, s = b>>3;
//   full c=x:    slot = c + 8*(j - 4c - 2)
//   full c>=8:   slot = (15-c) + 8*j
//   single c<=7: slot = c + 8*(64 + (j&3))
//   single c>=8: slot = (15-c) + 8*(66 + (j&3))
__global__ __launch_bounds__(256) void reduce_y(const short* __restrict__ Ypc,
                                                const float* __restrict__ Cvs,
                                                short* __restrict__ o) {
  int q = blockIdx.x;
  int j = q >> 5, qr = q & 31;
  int col = threadIdx.x * 4;
  float a0 = Cvs[col + 0], a1 = Cvs[col + 1], a2 = Cvs[col + 2], a3 = Cvs[col + 3];
  int cf = (j - 2) >> 2;                       // last full chunk (may be -1)
  for (int c = 0; c <= cf; c++) {
    int slot = (c <= 7) ? (c + 8 * (j - 4 * c - 2)) : ((15 - c) + 8 * j);
    const short* p = Ypc + ((size_t)slot * 32 + qr) * 1024 + col;
    short4v v = *(const short4v*)p;
    a0 += bf2f(v[0]); a1 += bf2f(v[1]); a2 += bf2f(v[2]); a3 += bf2f(v[3]);
  }
  if ((j & 3) < 2) {                           // diagonal single-group chunk
    int cp = j >> 2;
    int slot = (cp <= 7) ? (cp + 8 * (64 + (j & 3)))
                         : ((15 - cp) + 8 * (66 + (j & 3)));
    const short* p = Ypc + ((size_t)slot * 32 + qr) * 1024 + col;
    short4v v = *(const short4v*)p;
    a0 += bf2f(v[0]); a1 += bf2f(v[1]); a2 += bf2f(v[2]); a3 += bf2f(v[3]);
  }
  uint32_t u0 = cvt_pk_bf16(a0, a1), u1 = cvt_pk_bf16(a2, a3);
  short4v rr = { (short)u0, (short)(u0 >> 16), (short)u1, (short)(u1 >> 16) };
  *(short4v*)&o[(size_t)q * 1024 + col] = rr;
}

// ---------- QKV GEMM: [Q|K|V](+rope) = Xbf * WcatT^T; 64x96 tiles ----------
// grid (32, 32) = 1024 blocks = 4 blocks/CU.  4 waves as 2x2; wave tile
// 32x48 (acc[2][3]).  NEW (r15): V is written TRANSPOSED directly from the
// accumulator (acc r=0..3 are 4 consecutive q -> one short4 store along
// Vt's k-axis), and the V column-sum (Cvs) is accumulated here via one
// atomicAdd per lane per V-strip -- this eliminates the transpose_v kernel
// and the Vb round-trip entirely.  The mat branch is wave-uniform (16-wide
// strips are 16-aligned; mat boundaries are 1024-aligned), so the rope
// __shfl_xor stays in a uniformly-taken branch.
__global__ __launch_bounds__(256, 4)
void gemm_qkv(const short* __restrict__ A, const short* __restrict__ B,
              short* __restrict__ Qb, short* __restrict__ Kb,
              short* __restrict__ Vt, float* __restrict__ Cvs) {
  __shared__ __attribute__((aligned(16))) short lga[64 * 64];
  __shared__ __attribute__((aligned(16))) short lgb[96 * 64];
  const int tid = threadIdx.x;
  const int lane = tid & 63;
  const int w = tid >> 6;
  const int l15 = lane & 15;
  const int quad = lane >> 4;
  const int wm = w >> 1, wn = w & 1;
  const int m0 = blockIdx.x * 64, n0 = blockIdx.y * 96;
  const int rsub = lane >> 3;
  const int cpos = lane & 7;

  f32x4 acc[2][3];
#pragma unroll
  for (int i = 0; i < 2; i++)
#pragma unroll
    for (int j = 0; j < 3; j++) acc[i][j] = (f32x4){0.f, 0.f, 0.f, 0.f};

  for (int kb = 0; kb < 1024; kb += 64) {
    __syncthreads();
    int kc = cpos ^ rsub;
#pragma unroll
    for (int j = 0; j < 2; j++) {
      int r = (w * 2 + j) * 8 + rsub;
      gload_lds16(A + (size_t)(m0 + r) * 1024 + kb + kc * 8, &lga[(w * 2 + j) * 512]);
    }
#pragma unroll
    for (int j = 0; j < 3; j++) {
      int r = (w * 3 + j) * 8 + rsub;
      gload_lds16(B + (size_t)(n0 + r) * 1024 + kb + kc * 8, &lgb[(w * 3 + j) * 512]);
    }
    __syncthreads();
#pragma unroll
    for (int kk = 0; kk < 2; kk++) {
      bf16x8 af[2], bfr[3];
#pragma unroll
      for (int t = 0; t < 2; t++) {
        int row = wm * 32 + t * 16 + l15;
        int pc = (kk * 4 + quad) ^ (row & 7);
        af[t] = *(const bf16x8*)&lga[row * 64 + pc * 8];
      }
#pragma unroll
      for (int t = 0; t < 3; t++) {
        int rowb = wn * 48 + t * 16 + l15;
        int pcb = (kk * 4 + quad) ^ (rowb & 7);
        bfr[t] = *(const bf16x8*)&lgb[rowb * 64 + pcb * 8];
      }
#pragma unroll
      for (int mt = 0; mt < 2; mt++)
#pragma unroll
        for (int nt = 0; nt < 3; nt++)
          acc[mt][nt] = __builtin_amdgcn_mfma_f32_16x16x32_bf16(
              af[mt], bfr[nt], acc[mt][nt], 0, 0, 0);
    }
  }

#pragma unroll
  for (int nt = 0; nt < 3; nt++) {
    int n = n0 + wn * 48 + nt * 16 + l15;
    int mat = n >> 10;           // wave-uniform per nt
    int h = (n >> 6) & 15;
    int d = n & 63;
    if (mat < 2) {
      // Q/K with rope (shfl pairs even/odd d; wave-uniform branch)
#pragma unroll
      for (int mt = 0; mt < 2; mt++) {
#pragma unroll
        for (int r = 0; r < 4; r++) {
          int q = m0 + wm * 32 + mt * 16 + quad * 4 + r;
          float v = acc[mt][nt][r];
          float o = __shfl_xor(v, 1, 64);
          int i = d >> 1;
          float ang = (float)q * __builtin_exp2f(-(float)i * 0.2801807588956902f);
          float sn, cs;
          __sincosf(ang, &sn, &cs);
          float rv = (d & 1) ? (o * sn + v * cs) : (v * cs - o * sn);
          short* dst = (mat == 0) ? Qb : Kb;
          dst[((size_t)h * 2048 + q) * 64 + d] = f2bf(rv);
        }
      }
    } else {
      // V: transposed short4 store (r = 4 consecutive q) + fused column sum
      float vs = 0.f;
#pragma unroll
      for (int mt = 0; mt < 2; mt++) {
        int qb = m0 + wm * 32 + mt * 16 + quad * 4;
        short4v pv;
#pragma unroll
        for (int r = 0; r < 4; r++) {
          float v = acc[mt][nt][r];
          pv[r] = f2bf(v);
          vs += v;
        }
        *(short4v*)&Vt[((size_t)(h * 64 + d)) * 2048 + qb] = pv;
      }
      atomicAdd(&Cvs[h * 64 + d], vs * 0.0625f);
    }
  }
}

// ---------- output GEMM: out[2048x1024] = Ycbf * WoT^T; 64x64 tiles ----------
// grid (32,16) = 512 blocks = 2 independent blocks/CU (r13 win).  4 waves,
// wave tile 32x32 (acc[2][2]=16 VGPR, live ~50 << cap 128).  LDS 16KB.
__global__ __launch_bounds__(256, 4)
void gemm_o(const short* __restrict__ A, const short* __restrict__ B,
            float* __restrict__ C) {
  __shared__ __attribute__((aligned(16))) short lga[64 * 64];
  __shared__ __attribute__((aligned(16))) short lgb[64 * 64];
  const int tid = threadIdx.x;
  const int lane = tid & 63;
  const int w = tid >> 6;                      // 0..3
  const int l15 = lane & 15;
  const int quad = lane >> 4;
  const int wm = w >> 1, wn = w & 1;
  const int m0 = blockIdx.x * 64, n0 = blockIdx.y * 64;
  const int rsub = lane >> 3;
  const int cpos = lane & 7;

  f32x4 acc[2][2];
#pragma unroll
  for (int i = 0; i < 2; i++)
#pragma unroll
    for (int j = 0; j < 2; j++) acc[i][j] = (f32x4){0.f, 0.f, 0.f, 0.f};

  for (int kb = 0; kb < 1024; kb += 64) {
    __syncthreads();
    int kc = cpos ^ rsub;
#pragma unroll
    for (int j = 0; j < 2; j++) {
      int r = (w * 2 + j) * 8 + rsub;
      gload_lds16(A + (size_t)(m0 + r) * 1024 + kb + kc * 8, &lga[(w * 2 + j) * 512]);
      gload_lds16(B + (size_t)(n0 + r) * 1024 + kb + kc * 8, &lgb[(w * 2 + j) * 512]);
    }
    __syncthreads();
#pragma unroll
    for (int kk = 0; kk < 2; kk++) {
      bf16x8 af[2], bfr[2];
#pragma unroll
      for (int t = 0; t < 2; t++) {
        int row = wm * 32 + t * 16 + l15;
        int pc = (kk * 4 + quad) ^ (row & 7);
        af[t] = *(const bf16x8*)&lga[row * 64 + pc * 8];
        int rowb = wn * 32 + t * 16 + l15;
        int pcb = (kk * 4 + quad) ^ (rowb & 7);
        bfr[t] = *(const bf16x8*)&lgb[rowb * 64 + pcb * 8];
      }
#pragma unroll
      for (int mt = 0; mt < 2; mt++)
#pragma unroll
        for (int nt = 0; nt < 2; nt++)
          acc[mt][nt] = __builtin_amdgcn_mfma_f32_16x16x32_bf16(
              af[mt], bfr[nt], acc[mt][nt], 0, 0, 0);
    }
  }

#pragma unroll
  for (int mt = 0; mt < 2; mt++) {
    int q = m0 + wm * 32 + mt * 16 + quad * 4;
#pragma unroll
    for (int nt = 0; nt < 2; nt++) {
      int n = n0 + wn * 32 + nt * 16 + l15;
#pragma unroll
      for (int r = 0; r < 4; r++) C[(size_t)(q + r) * 1024 + n] = acc[mt][nt][r];
    }
  }
}

// ---------- causal attention, head-axis softmax, A' = A - 1/16 ----------
// EXACT round-6/9/10 kernel (best measured: 68-70 us attn) -- FROZEN.
// 32-row q-tiles; XCD-pinned balanced chunk map; 1024 thr = 16 waves = 16
// heads; LDS 73728 -> 2 blocks/CU; (1024,2) -> VGPR cap 64, no spill.
// Q=32 geometry is the amortization optimum reachable under the 2048
// thread/CU limit (r11 lesson: Q=16 quadruples per-row K/V load cost).
__global__ __launch_bounds__(1024, 2)
void attn_kernel(const short* __restrict__ Qb, const short* __restrict__ Kb,
                 const short* __restrict__ Vt, short* __restrict__ Ypc) {
  __shared__ short Sb[16 * 32 * 72];   // [h][q 32][72: 64 k + pad], in-place
  const int tid = threadIdx.x;
  const int lane = tid & 63;
  const int h = tid >> 6;                    // wave = head, 0..15
  const int l15 = lane & 15, quad = lane >> 4;
  const int b = blockIdx.x;
  const int x = b & 7, s = b >> 3;
  int c, j, ng;
  const int n1 = 62 - 4 * x;                 // full chunks with c = x
  if (s < n1)      { c = x;      j = 4 * x + 2 + s;        ng = 2; }
  else if (s < 64) { c = 15 - x; j = s;                    ng = 2; }
  else if (s < 66) { c = x;      j = 4 * x + (s - 64);     ng = 1; }
  else             { c = 15 - x; j = 60 - 4 * x + (s - 66); ng = 1; }
  const int q0 = j * 32;
  const int g0 = 2 * c;

  bf16x8 qf[2][2];                           // [qsub][half-of-d]
#pragma unroll
  for (int qs = 0; qs < 2; qs++)
#pragma unroll
    for (int cc = 0; cc < 2; cc++)
      qf[qs][cc] = *(const bf16x8*)&Qb[((size_t)h * 2048 + q0 + qs * 16 + l15) * 64 +
                                       cc * 32 + quad * 8];

  f32x4 yacc[2][4];                          // [qsub][nt]
#pragma unroll
  for (int i = 0; i < 2; i++)
#pragma unroll
    for (int jj = 0; jj < 4; jj++) yacc[i][jj] = (f32x4){0.f, 0.f, 0.f, 0.f};

  for (int gi = 0; gi < ng; gi++) {
    const int k0 = (g0 + gi) * 64;
    // ---- S = (QK^T) * 0.125*log2e -> bf16 LDS [h][q 32][72] ----
#pragma unroll
    for (int st = 0; st < 4; st++) {
      const short* kb = &Kb[((size_t)h * 2048 + k0 + st * 16 + l15) * 64 + quad * 8];
      bf16x8 kf0 = *(const bf16x8*)kb;
      bf16x8 kf1 = *(const bf16x8*)(kb + 32);
#pragma unroll
      for (int qs = 0; qs < 2; qs++) {
        f32x4 sa = (f32x4){0.f, 0.f, 0.f, 0.f};
        sa = __builtin_amdgcn_mfma_f32_16x16x32_bf16(qf[qs][0], kf0, sa, 0, 0, 0);
        sa = __builtin_amdgcn_mfma_f32_16x16x32_bf16(qf[qs][1], kf1, sa, 0, 0, 0);
        const float cs = 0.18033688011112042f;   // 0.125 * log2(e)
        uint32_t u0 = cvt_pk_bf16(sa[0] * cs, sa[1] * cs);
        uint32_t u1 = cvt_pk_bf16(sa[2] * cs, sa[3] * cs);
        int rb = (h * 32 + qs * 16 + quad * 4) * 72 + st * 16 + l15;
        Sb[rb]       = (short)u0;
        Sb[rb + 72]  = (short)(u0 >> 16);
        Sb[rb + 144] = (short)u1;
        Sb[rb + 216] = (short)(u1 >> 16);
      }
    }
    __syncthreads();
    // ---- head-axis softmax IN PLACE (no max-sub); A' = softmax - 1/16 ----
    // 32q x 64k = 2048 positions, 1024 threads, 2 per thread (sequential).
#pragma unroll
    for (int pp = 0; pp < 2; pp++) {
      int p = tid + pp * 1024;
      int q = p >> 6, kl = p & 63;
      int base = q * 72 + kl;
      float t[16];
      float sum = 0.f;
#pragma unroll
      for (int hh = 0; hh < 16; hh++) {
        float e = __builtin_exp2f(bf2f(Sb[hh * 2304 + base]));
        t[hh] = e;
        sum += e;
      }
      bool msk = (k0 + kl) > (q0 + q);
      float rs = msk ? 0.f : 1.f / sum;
      float offv = msk ? 0.f : 0.0625f;
#pragma unroll
      for (int hh = 0; hh < 16; hh += 2) {
        uint32_t u = cvt_pk_bf16(t[hh] * rs - offv, t[hh + 1] * rs - offv);
        Sb[hh * 2304 + base]       = (short)u;
        Sb[(hh + 1) * 2304 + base] = (short)(u >> 16);
      }
    }
    __syncthreads();
    // ---- Y += A' @ V ---- (V frag per (kk,nt) loaded once, both qsubs)
#pragma unroll
    for (int kk = 0; kk < 2; kk++) {
      bf16x8 af0 = *(const bf16x8*)&Sb[(h * 32 + l15) * 72 + kk * 32 + quad * 8];
      bf16x8 af1 = *(const bf16x8*)&Sb[(h * 32 + 16 + l15) * 72 + kk * 32 + quad * 8];
#pragma unroll
      for (int nt = 0; nt < 4; nt++) {
        bf16x8 vf = *(const bf16x8*)&Vt[((size_t)h * 64 + nt * 16 + l15) * 2048 +
                                        k0 + kk * 32 + quad * 8];
        yacc[0][nt] = __builtin_amdgcn_mfma_f32_16x16x32_bf16(af0, vf, yacc[0][nt],
                                                              0, 0, 0);
        yacc[1][nt] = __builtin_amdgcn_mfma_f32_16x16x32_bf16(af1, vf, yacc[1][nt],
                                                              0, 0, 0);
      }
    }
    __syncthreads();
  }
  // write compact bf16 partial at chunk slot b: [32 q-rows][1024 cols]
  short* Y = Ypc + (size_t)b * 32 * 1024;
#pragma unroll
  for (int qs = 0; qs < 2; qs++) {
#pragma unroll
    for (int nt = 0; nt < 4; nt++) {
      int col = h * 64 + nt * 16 + l15;
#pragma unroll
      for (int rr = 0; rr < 4; rr++)
        Y[(size_t)(qs * 16 + quad * 4 + rr) * 1024 + col] = f2bf(yacc[qs][nt][rr]);
    }
  }
}

// ---------- host ----------
extern "C" void kernel_launch(void* const* d_in, const int* in_sizes, int n_in,
                              void* d_out, int out_size, void* d_ws, size_t ws_size,
                              hipStream_t stream) {
  (void)in_sizes; (void)n_in; (void)out_size; (void)ws_size;
  const float* X  = (const float*)d_in[0];
  const float* Wq = (const float*)d_in[2];
  const float* Wk = (const float*)d_in[3];
  const float* Wv = (const float*)d_in[4];
  const float* Wo = (const float*)d_in[5];
  char* ws = (char*)d_ws;
  const size_t MB = 1024 * 1024;
  short* Xbf   = (short*)(ws + 0);        // 4 MB; reused as Ycbf after gemm_qkv
  short* WcatT = (short*)(ws + 4 * MB);   // 6 MB [3072 n][1024 k]
  short* WoT   = (short*)(ws + 10 * MB);  // 2 MB [1024 n][1024 k]
  short* Qb    = (short*)(ws + 12 * MB);  // 4 MB [h][q][64]
  short* Kb    = (short*)(ws + 16 * MB);  // 4 MB [h][k][64]
  // ws+20MB: 4 MB free (Vb eliminated -- V written transposed by gemm_qkv)
  short* Vt    = (short*)(ws + 24 * MB);  // 4 MB [h][d][2048]
  short* Ypc   = (short*)(ws + 28 * MB);  // 34 MB: 544 chunk partials [32][1024]
  float* Cvs   = (float*)(ws + 63 * MB);  // 4 KB
  short* Ycbf  = Xbf;                     // alias (Xbf dead after gemm_qkv)
  float* out   = (float*)d_out;

  prep<<<dim3(6144), dim3(256), 0, stream>>>(X, Wq, Wk, Wv, Wo, Xbf, WcatT, WoT, Cvs);
  gemm_qkv<<<dim3(32, 32), dim3(256), 0, stream>>>(Xbf, WcatT, Qb, Kb, Vt, Cvs);
  attn_kernel<<<dim3(544), dim3(1024), 0, stream>>>(Qb, Kb, Vt, Ypc);
  reduce_y<<<dim3(2048), dim3(256), 0, stream>>>(Ypc, Cvs, Ycbf);
  gemm_o<<<dim3(32, 16), dim3(256), 0, stream>>>(Ycbf, WoT, out);
}

// Round 16
// 196.221 us; speedup vs baseline: 1.1350x; 1.1350x over previous
//
#include <hip/hip_runtime.h>
#include <stdint.h>
#include <stddef.h>
#include <math.h>

// ---------- types ----------
typedef __attribute__((ext_vector_type(8))) short bf16x8;   // 8 bf16 = 4 VGPRs
typedef __attribute__((ext_vector_type(4))) short short4v;
typedef __attribute__((ext_vector_type(4))) float f32x4;

// bf16 round-to-nearest-even from fp32
__device__ __forceinline__ short f2bf(float f) {
  union { float f; uint32_t u; } x; x.f = f;
  return (short)((x.u + 0x7fffu + ((x.u >> 16) & 1u)) >> 16);
}
__device__ __forceinline__ float bf2f(short s) {
  union { uint32_t u; float f; } x; x.u = ((uint32_t)(uint16_t)s) << 16;
  return x.f;
}
// pack 2 fp32 -> 2 bf16 (RTNE) in one instruction
__device__ __forceinline__ uint32_t cvt_pk_bf16(float a, float b) {
  uint32_t r;
  asm("v_cvt_pk_bf16_f32 %0, %1, %2" : "=v"(r) : "v"(a), "v"(b));
  return r;
}

// async global->LDS, 16B per lane; lds base must be wave-uniform
__device__ __forceinline__ void gload_lds16(const void* g, void* lds) {
  __builtin_amdgcn_global_load_lds(
      (const __attribute__((address_space(1))) void*)g,
      (__attribute__((address_space(3))) void*)lds, 16, 0, 0);
}

// ---------- fused prep: X cast (blocks 0..2047) + W transpose-cast (2048..6143)
// cast block 0 also zeroes Cvs (stream-ordered before transpose_v's atomics).
__global__ __launch_bounds__(256) void prep(const float* __restrict__ X,
                                            const float* __restrict__ Wq,
                                            const float* __restrict__ Wk,
                                            const float* __restrict__ Wv,
                                            const float* __restrict__ Wo,
                                            short* __restrict__ Xbf,
                                            short* __restrict__ WcatT,
                                            short* __restrict__ WoT,
                                            float* __restrict__ Cvs) {
  __shared__ float tl[32][33];
  int bid = blockIdx.x;
  if (bid < 2048) {
    if (bid == 0) {
      int c4 = threadIdx.x * 4;
      Cvs[c4] = 0.f; Cvs[c4 + 1] = 0.f; Cvs[c4 + 2] = 0.f; Cvs[c4 + 3] = 0.f;
    }
    int i4 = (bid * 256 + threadIdx.x) * 4;
    float4 v = *(const float4*)&X[i4];
    short4v r = { f2bf(v.x), f2bf(v.y), f2bf(v.z), f2bf(v.w) };
    *(short4v*)&Xbf[i4] = r;
  } else {
    int wb = bid - 2048;           // 0..4095
    int z = wb >> 10;              // matrix 0..3
    int bx = (wb >> 5) & 31;       // k-tile
    int by = wb & 31;              // n-tile
    const float* src = (z == 0) ? Wq : (z == 1) ? Wk : (z == 2) ? Wv : Wo;
    short* dst = (z == 3) ? WoT : WcatT + (size_t)z * 1024 * 1024;
    int tx = threadIdx.x & 31, ty = threadIdx.x >> 5;  // 32 x 8
    int kk0 = bx * 32;   // src rows (k)
    int nn0 = by * 32;   // src cols (n)
#pragma unroll
    for (int j = 0; j < 4; j++)
      tl[ty + j * 8][tx] = src[(size_t)(kk0 + ty + j * 8) * 1024 + nn0 + tx];
    __syncthreads();
#pragma unroll
    for (int j = 0; j < 4; j++)
      dst[(size_t)(nn0 + ty + j * 8) * 1024 + kk0 + tx] = f2bf(tl[tx][ty + j * 8]);
  }
}

// gather-reduce over 32-row chunk partials, XCD-pinned slot map (round 6).
// chunk (c, j): k-groups {2c, 2c+1} (full, j >= 4c+2) or {2c} (single,
// j in {4c, 4c+1}).  Forward map (see attn_kernel): XCD x = b&7, s = b>>3;
//   full c=x:    slot = c + 8*(j - 4c - 2)
//   full c>=8:   slot = (15-c) + 8*j
//   single c<=7: slot = c + 8*(64 + (j&3))
//   single c>=8: slot = (15-c) + 8*(66 + (j&3))
__global__ __launch_bounds__(256) void reduce_y(const short* __restrict__ Ypc,
                                                const float* __restrict__ Cvs,
                                                short* __restrict__ o) {
  int q = blockIdx.x;
  int j = q >> 5, qr = q & 31;
  int col = threadIdx.x * 4;
  float a0 = Cvs[col + 0], a1 = Cvs[col + 1], a2 = Cvs[col + 2], a3 = Cvs[col + 3];
  int cf = (j - 2) >> 2;                       // last full chunk (may be -1)
  for (int c = 0; c <= cf; c++) {
    int slot = (c <= 7) ? (c + 8 * (j - 4 * c - 2)) : ((15 - c) + 8 * j);
    const short* p = Ypc + ((size_t)slot * 32 + qr) * 1024 + col;
    short4v v = *(const short4v*)p;
    a0 += bf2f(v[0]); a1 += bf2f(v[1]); a2 += bf2f(v[2]); a3 += bf2f(v[3]);
  }
  if ((j & 3) < 2) {                           // diagonal single-group chunk
    int cp = j >> 2;
    int slot = (cp <= 7) ? (cp + 8 * (64 + (j & 3)))
                         : ((15 - cp) + 8 * (66 + (j & 3)));
    const short* p = Ypc + ((size_t)slot * 32 + qr) * 1024 + col;
    short4v v = *(const short4v*)p;
    a0 += bf2f(v[0]); a1 += bf2f(v[1]); a2 += bf2f(v[2]); a3 += bf2f(v[3]);
  }
  uint32_t u0 = cvt_pk_bf16(a0, a1), u1 = cvt_pk_bf16(a2, a3);
  short4v rr = { (short)u0, (short)(u0 >> 16), (short)u1, (short)(u1 >> 16) };
  *(short4v*)&o[(size_t)q * 1024 + col] = rr;
}

// V [h][k 2048][d 64] -> Vt [h][d 64][k 2048]; fused vsum: each block
// atomically accumulates (1/16)*sum over its 64 k of V[h][k][d] into Cvs.
// (r15 lesson: fusing this into gemm_qkv's epilogue scatters 8B stores at
// 4KB stride -> ~16x write amplification; the LDS-staged transpose here is
// the cheap correct way.)
__global__ __launch_bounds__(256) void transpose_v(const short* __restrict__ Vb,
                                                   short* __restrict__ Vt,
                                                   float* __restrict__ Cvs) {
  __shared__ short tv[64][72];
  int h = blockIdx.y, k0 = blockIdx.x * 64;
  int tid = threadIdx.x;
#pragma unroll
  for (int j = 0; j < 2; j++) {
    int idx = tid + j * 256;
    int row = idx >> 3, c = idx & 7;
    bf16x8 v = *(const bf16x8*)&Vb[((size_t)h * 2048 + k0 + row) * 64 + c * 8];
#pragma unroll
    for (int t = 0; t < 8; t++) tv[row][c * 8 + t] = v[t];
  }
  __syncthreads();
#pragma unroll
  for (int j = 0; j < 2; j++) {
    int idx = tid + j * 256;
    int d = idx >> 3, c = idx & 7;
    bf16x8 v;
#pragma unroll
    for (int t = 0; t < 8; t++) v[t] = tv[c * 8 + t][d];
    *(bf16x8*)&Vt[((size_t)h * 64 + d) * 2048 + k0 + c * 8] = v;
  }
  // fused vsum: column-sum of the staged tile (tv unchanged by phase 2)
  if (tid < 64) {
    float s = 0.f;
#pragma unroll 8
    for (int k = 0; k < 64; k++) s += bf2f(tv[k][tid]);
    atomicAdd(&Cvs[h * 64 + tid], s * 0.0625f);
  }
}

// ---------- QKV GEMM: [Q|K|V](+rope) = Xbf * WcatT^T; 64x96 tiles ----------
// grid (32, 32) = 1024 blocks = 4 blocks/CU.  4 waves as 2x2; wave tile
// 32x48 (acc[2][3]); LDS 20KB; live ~80 VGPR << cap 128.
__global__ __launch_bounds__(256, 4)
void gemm_qkv(const short* __restrict__ A, const short* __restrict__ B,
              short* __restrict__ Qb, short* __restrict__ Kb,
              short* __restrict__ Vb) {
  __shared__ __attribute__((aligned(16))) short lga[64 * 64];
  __shared__ __attribute__((aligned(16))) short lgb[96 * 64];
  const int tid = threadIdx.x;
  const int lane = tid & 63;
  const int w = tid >> 6;
  const int l15 = lane & 15;
  const int quad = lane >> 4;
  const int wm = w >> 1, wn = w & 1;
  const int m0 = blockIdx.x * 64, n0 = blockIdx.y * 96;
  const int rsub = lane >> 3;
  const int cpos = lane & 7;

  f32x4 acc[2][3];
#pragma unroll
  for (int i = 0; i < 2; i++)
#pragma unroll
    for (int j = 0; j < 3; j++) acc[i][j] = (f32x4){0.f, 0.f, 0.f, 0.f};

  for (int kb = 0; kb < 1024; kb += 64) {
    __syncthreads();
    int kc = cpos ^ rsub;
#pragma unroll
    for (int j = 0; j < 2; j++) {
      int r = (w * 2 + j) * 8 + rsub;
      gload_lds16(A + (size_t)(m0 + r) * 1024 + kb + kc * 8, &lga[(w * 2 + j) * 512]);
    }
#pragma unroll
    for (int j = 0; j < 3; j++) {
      int r = (w * 3 + j) * 8 + rsub;
      gload_lds16(B + (size_t)(n0 + r) * 1024 + kb + kc * 8, &lgb[(w * 3 + j) * 512]);
    }
    __syncthreads();
#pragma unroll
    for (int kk = 0; kk < 2; kk++) {
      bf16x8 af[2], bfr[3];
#pragma unroll
      for (int t = 0; t < 2; t++) {
        int row = wm * 32 + t * 16 + l15;
        int pc = (kk * 4 + quad) ^ (row & 7);
        af[t] = *(const bf16x8*)&lga[row * 64 + pc * 8];
      }
#pragma unroll
      for (int t = 0; t < 3; t++) {
        int rowb = wn * 48 + t * 16 + l15;
        int pcb = (kk * 4 + quad) ^ (rowb & 7);
        bfr[t] = *(const bf16x8*)&lgb[rowb * 64 + pcb * 8];
      }
#pragma unroll
      for (int mt = 0; mt < 2; mt++)
#pragma unroll
        for (int nt = 0; nt < 3; nt++)
          acc[mt][nt] = __builtin_amdgcn_mfma_f32_16x16x32_bf16(
              af[mt], bfr[nt], acc[mt][nt], 0, 0, 0);
    }
  }

#pragma unroll
  for (int mt = 0; mt < 2; mt++) {
#pragma unroll
    for (int nt = 0; nt < 3; nt++) {
      int n = n0 + wn * 48 + nt * 16 + l15;
      int mat = n >> 10;
      int h = (n >> 6) & 15;
      int d = n & 63;
#pragma unroll
      for (int r = 0; r < 4; r++) {
        int q = m0 + wm * 32 + mt * 16 + quad * 4 + r;
        float v = acc[mt][nt][r];
        float o = __shfl_xor(v, 1, 64);
        if (mat < 2) {
          int i = d >> 1;
          float ang = (float)q * __builtin_exp2f(-(float)i * 0.2801807588956902f);
          float sn, cs;
          __sincosf(ang, &sn, &cs);
          float rv = (d & 1) ? (o * sn + v * cs) : (v * cs - o * sn);
          short* dst = (mat == 0) ? Qb : Kb;
          dst[((size_t)h * 2048 + q) * 64 + d] = f2bf(rv);
        } else {
          Vb[((size_t)h * 2048 + q) * 64 + d] = f2bf(v);
        }
      }
    }
  }
}

// ---------- output GEMM: out[2048x1024] = Ycbf * WoT^T; 64x64 tiles ----------
// grid (32,16) = 512 blocks = 2 independent blocks/CU (r13 win).  4 waves,
// wave tile 32x32 (acc[2][2]=16 VGPR, live ~50 << cap 128).  LDS 16KB.
__global__ __launch_bounds__(256, 4)
void gemm_o(const short* __restrict__ A, const short* __restrict__ B,
            float* __restrict__ C) {
  __shared__ __attribute__((aligned(16))) short lga[64 * 64];
  __shared__ __attribute__((aligned(16))) short lgb[64 * 64];
  const int tid = threadIdx.x;
  const int lane = tid & 63;
  const int w = tid >> 6;                      // 0..3
  const int l15 = lane & 15;
  const int quad = lane >> 4;
  const int wm = w >> 1, wn = w & 1;
  const int m0 = blockIdx.x * 64, n0 = blockIdx.y * 64;
  const int rsub = lane >> 3;
  const int cpos = lane & 7;

  f32x4 acc[2][2];
#pragma unroll
  for (int i = 0; i < 2; i++)
#pragma unroll
    for (int j = 0; j < 2; j++) acc[i][j] = (f32x4){0.f, 0.f, 0.f, 0.f};

  for (int kb = 0; kb < 1024; kb += 64) {
    __syncthreads();
    int kc = cpos ^ rsub;
#pragma unroll
    for (int j = 0; j < 2; j++) {
      int r = (w * 2 + j) * 8 + rsub;
      gload_lds16(A + (size_t)(m0 + r) * 1024 + kb + kc * 8, &lga[(w * 2 + j) * 512]);
      gload_lds16(B + (size_t)(n0 + r) * 1024 + kb + kc * 8, &lgb[(w * 2 + j) * 512]);
    }
    __syncthreads();
#pragma unroll
    for (int kk = 0; kk < 2; kk++) {
      bf16x8 af[2], bfr[2];
#pragma unroll
      for (int t = 0; t < 2; t++) {
        int row = wm * 32 + t * 16 + l15;
        int pc = (kk * 4 + quad) ^ (row & 7);
        af[t] = *(const bf16x8*)&lga[row * 64 + pc * 8];
        int rowb = wn * 32 + t * 16 + l15;
        int pcb = (kk * 4 + quad) ^ (rowb & 7);
        bfr[t] = *(const bf16x8*)&lgb[rowb * 64 + pcb * 8];
      }
#pragma unroll
      for (int mt = 0; mt < 2; mt++)
#pragma unroll
        for (int nt = 0; nt < 2; nt++)
          acc[mt][nt] = __builtin_amdgcn_mfma_f32_16x16x32_bf16(
              af[mt], bfr[nt], acc[mt][nt], 0, 0, 0);
    }
  }

#pragma unroll
  for (int mt = 0; mt < 2; mt++) {
    int q = m0 + wm * 32 + mt * 16 + quad * 4;
#pragma unroll
    for (int nt = 0; nt < 2; nt++) {
      int n = n0 + wn * 32 + nt * 16 + l15;
#pragma unroll
      for (int r = 0; r < 4; r++) C[(size_t)(q + r) * 1024 + n] = acc[mt][nt][r];
    }
  }
}

// ---------- causal attention, head-axis softmax, A' = A - 1/16 ----------
// EXACT round-6/9/10 kernel (best measured: 68-70 us attn) -- FROZEN.
// 32-row q-tiles; XCD-pinned balanced chunk map; 1024 thr = 16 waves = 16
// heads; LDS 73728 -> 2 blocks/CU; (1024,2) -> VGPR cap 64, no spill.
// Q=32 geometry is the amortization optimum reachable under the 2048
// thread/CU limit (r11 lesson: Q=16 quadruples per-row K/V load cost).
__global__ __launch_bounds__(1024, 2)
void attn_kernel(const short* __restrict__ Qb, const short* __restrict__ Kb,
                 const short* __restrict__ Vt, short* __restrict__ Ypc) {
  __shared__ short Sb[16 * 32 * 72];   // [h][q 32][72: 64 k + pad], in-place
  const int tid = threadIdx.x;
  const int lane = tid & 63;
  const int h = tid >> 6;                    // wave = head, 0..15
  const int l15 = lane & 15, quad = lane >> 4;
  const int b = blockIdx.x;
  const int x = b & 7, s = b >> 3;
  int c, j, ng;
  const int n1 = 62 - 4 * x;                 // full chunks with c = x
  if (s < n1)      { c = x;      j = 4 * x + 2 + s;        ng = 2; }
  else if (s < 64) { c = 15 - x; j = s;                    ng = 2; }
  else if (s < 66) { c = x;      j = 4 * x + (s - 64);     ng = 1; }
  else             { c = 15 - x; j = 60 - 4 * x + (s - 66); ng = 1; }
  const int q0 = j * 32;
  const int g0 = 2 * c;

  bf16x8 qf[2][2];                           // [qsub][half-of-d]
#pragma unroll
  for (int qs = 0; qs < 2; qs++)
#pragma unroll
    for (int cc = 0; cc < 2; cc++)
      qf[qs][cc] = *(const bf16x8*)&Qb[((size_t)h * 2048 + q0 + qs * 16 + l15) * 64 +
                                       cc * 32 + quad * 8];

  f32x4 yacc[2][4];                          // [qsub][nt]
#pragma unroll
  for (int i = 0; i < 2; i++)
#pragma unroll
    for (int jj = 0; jj < 4; jj++) yacc[i][jj] = (f32x4){0.f, 0.f, 0.f, 0.f};

  for (int gi = 0; gi < ng; gi++) {
    const int k0 = (g0 + gi) * 64;
    // ---- S = (QK^T) * 0.125*log2e -> bf16 LDS [h][q 32][72] ----
#pragma unroll
    for (int st = 0; st < 4; st++) {
      const short* kb = &Kb[((size_t)h * 2048 + k0 + st * 16 + l15) * 64 + quad * 8];
      bf16x8 kf0 = *(const bf16x8*)kb;
      bf16x8 kf1 = *(const bf16x8*)(kb + 32);
#pragma unroll
      for (int qs = 0; qs < 2; qs++) {
        f32x4 sa = (f32x4){0.f, 0.f, 0.f, 0.f};
        sa = __builtin_amdgcn_mfma_f32_16x16x32_bf16(qf[qs][0], kf0, sa, 0, 0, 0);
        sa = __builtin_amdgcn_mfma_f32_16x16x32_bf16(qf[qs][1], kf1, sa, 0, 0, 0);
        const float cs = 0.18033688011112042f;   // 0.125 * log2(e)
        uint32_t u0 = cvt_pk_bf16(sa[0] * cs, sa[1] * cs);
        uint32_t u1 = cvt_pk_bf16(sa[2] * cs, sa[3] * cs);
        int rb = (h * 32 + qs * 16 + quad * 4) * 72 + st * 16 + l15;
        Sb[rb]       = (short)u0;
        Sb[rb + 72]  = (short)(u0 >> 16);
        Sb[rb + 144] = (short)u1;
        Sb[rb + 216] = (short)(u1 >> 16);
      }
    }
    __syncthreads();
    // ---- head-axis softmax IN PLACE (no max-sub); A' = softmax - 1/16 ----
    // 32q x 64k = 2048 positions, 1024 threads, 2 per thread (sequential).
#pragma unroll
    for (int pp = 0; pp < 2; pp++) {
      int p = tid + pp * 1024;
      int q = p >> 6, kl = p & 63;
      int base = q * 72 + kl;
      float t[16];
      float sum = 0.f;
#pragma unroll
      for (int hh = 0; hh < 16; hh++) {
        float e = __builtin_exp2f(bf2f(Sb[hh * 2304 + base]));
        t[hh] = e;
        sum += e;
      }
      bool msk = (k0 + kl) > (q0 + q);
      float rs = msk ? 0.f : 1.f / sum;
      float offv = msk ? 0.f : 0.0625f;
#pragma unroll
      for (int hh = 0; hh < 16; hh += 2) {
        uint32_t u = cvt_pk_bf16(t[hh] * rs - offv, t[hh + 1] * rs - offv);
        Sb[hh * 2304 + base]       = (short)u;
        Sb[(hh + 1) * 2304 + base] = (short)(u >> 16);
      }
    }
    __syncthreads();
    // ---- Y += A' @ V ---- (V frag per (kk,nt) loaded once, both qsubs)
#pragma unroll
    for (int kk = 0; kk < 2; kk++) {
      bf16x8 af0 = *(const bf16x8*)&Sb[(h * 32 + l15) * 72 + kk * 32 + quad * 8];
      bf16x8 af1 = *(const bf16x8*)&Sb[(h * 32 + 16 + l15) * 72 + kk * 32 + quad * 8];
#pragma unroll
      for (int nt = 0; nt < 4; nt++) {
        bf16x8 vf = *(const bf16x8*)&Vt[((size_t)h * 64 + nt * 16 + l15) * 2048 +
                                        k0 + kk * 32 + quad * 8];
        yacc[0][nt] = __builtin_amdgcn_mfma_f32_16x16x32_bf16(af0, vf, yacc[0][nt],
                                                              0, 0, 0);
        yacc[1][nt] = __builtin_amdgcn_mfma_f32_16x16x32_bf16(af1, vf, yacc[1][nt],
                                                              0, 0, 0);
      }
    }
    __syncthreads();
  }
  // write compact bf16 partial at chunk slot b: [32 q-rows][1024 cols]
  short* Y = Ypc + (size_t)b * 32 * 1024;
#pragma unroll
  for (int qs = 0; qs < 2; qs++) {
#pragma unroll
    for (int nt = 0; nt < 4; nt++) {
      int col = h * 64 + nt * 16 + l15;
#pragma unroll
      for (int rr = 0; rr < 4; rr++)
        Y[(size_t)(qs * 16 + quad * 4 + rr) * 1024 + col] = f2bf(yacc[qs][nt][rr]);
    }
  }
}

// ---------- host ----------
extern "C" void kernel_launch(void* const* d_in, const int* in_sizes, int n_in,
                              void* d_out, int out_size, void* d_ws, size_t ws_size,
                              hipStream_t stream) {
  (void)in_sizes; (void)n_in; (void)out_size; (void)ws_size;
  const float* X  = (const float*)d_in[0];
  const float* Wq = (const float*)d_in[2];
  const float* Wk = (const float*)d_in[3];
  const float* Wv = (const float*)d_in[4];
  const float* Wo = (const float*)d_in[5];
  char* ws = (char*)d_ws;
  const size_t MB = 1024 * 1024;
  short* Xbf   = (short*)(ws + 0);        // 4 MB; reused as Ycbf after gemm_qkv
  short* WcatT = (short*)(ws + 4 * MB);   // 6 MB [3072 n][1024 k]
  short* WoT   = (short*)(ws + 10 * MB);  // 2 MB [1024 n][1024 k]
  short* Qb    = (short*)(ws + 12 * MB);  // 4 MB [h][q][64]
  short* Kb    = (short*)(ws + 16 * MB);  // 4 MB [h][k][64]
  short* Vb    = (short*)(ws + 20 * MB);  // 4 MB [h][k][64]
  short* Vt    = (short*)(ws + 24 * MB);  // 4 MB [h][d][2048]
  short* Ypc   = (short*)(ws + 28 * MB);  // 34 MB: 544 chunk partials [32][1024]
  float* Cvs   = (float*)(ws + 63 * MB);  // 4 KB
  short* Ycbf  = Xbf;                     // alias (Xbf dead after gemm_qkv)
  float* out   = (float*)d_out;

  prep<<<dim3(6144), dim3(256), 0, stream>>>(X, Wq, Wk, Wv, Wo, Xbf, WcatT, WoT, Cvs);
  gemm_qkv<<<dim3(32, 32), dim3(256), 0, stream>>>(Xbf, WcatT, Qb, Kb, Vb);
  transpose_v<<<dim3(32, 16), dim3(256), 0, stream>>>(Vb, Vt, Cvs);
  attn_kernel<<<dim3(544), dim3(1024), 0, stream>>>(Qb, Kb, Vt, Ypc);
  reduce_y<<<dim3(2048), dim3(256), 0, stream>>>(Ypc, Cvs, Ycbf);
  gemm_o<<<dim3(32, 16), dim3(256), 0, stream>>>(Ycbf, WoT, out);
}

// Round 17
// 195.026 us; speedup vs baseline: 1.1420x; 1.0061x over previous
//
#include <hip/hip_runtime.h>
#include <stdint.h>
#include <stddef.h>
#include <math.h>

// ---------- types ----------
typedef __attribute__((ext_vector_type(8))) short bf16x8;   // 8 bf16 = 4 VGPRs
typedef __attribute__((ext_vector_type(4))) short short4v;
typedef __attribute__((ext_vector_type(4))) float f32x4;

// bf16 round-to-nearest-even from fp32
__device__ __forceinline__ short f2bf(float f) {
  union { float f; uint32_t u; } x; x.f = f;
  return (short)((x.u + 0x7fffu + ((x.u >> 16) & 1u)) >> 16);
}
__device__ __forceinline__ float bf2f(short s) {
  union { uint32_t u; float f; } x; x.u = ((uint32_t)(uint16_t)s) << 16;
  return x.f;
}
// pack 2 fp32 -> 2 bf16 (RTNE) in one instruction
__device__ __forceinline__ uint32_t cvt_pk_bf16(float a, float b) {
  uint32_t r;
  asm("v_cvt_pk_bf16_f32 %0, %1, %2" : "=v"(r) : "v"(a), "v"(b));
  return r;
}

// async global->LDS, 16B per lane; lds base must be wave-uniform
__device__ __forceinline__ void gload_lds16(const void* g, void* lds) {
  __builtin_amdgcn_global_load_lds(
      (const __attribute__((address_space(1))) void*)g,
      (__attribute__((address_space(3))) void*)lds, 16, 0, 0);
}

// ---------- fused prep: X cast (blocks 0..2047) + W transpose-cast (2048..6143)
// cast block 0 also zeroes Cvs (stream-ordered before transpose_v's atomics).
__global__ __launch_bounds__(256) void prep(const float* __restrict__ X,
                                            const float* __restrict__ Wq,
                                            const float* __restrict__ Wk,
                                            const float* __restrict__ Wv,
                                            const float* __restrict__ Wo,
                                            short* __restrict__ Xbf,
                                            short* __restrict__ WcatT,
                                            short* __restrict__ WoT,
                                            float* __restrict__ Cvs) {
  __shared__ float tl[32][33];
  int bid = blockIdx.x;
  if (bid < 2048) {
    if (bid == 0) {
      int c4 = threadIdx.x * 4;
      Cvs[c4] = 0.f; Cvs[c4 + 1] = 0.f; Cvs[c4 + 2] = 0.f; Cvs[c4 + 3] = 0.f;
    }
    int i4 = (bid * 256 + threadIdx.x) * 4;
    float4 v = *(const float4*)&X[i4];
    short4v r = { f2bf(v.x), f2bf(v.y), f2bf(v.z), f2bf(v.w) };
    *(short4v*)&Xbf[i4] = r;
  } else {
    int wb = bid - 2048;           // 0..4095
    int z = wb >> 10;              // matrix 0..3
    int bx = (wb >> 5) & 31;       // k-tile
    int by = wb & 31;              // n-tile
    const float* src = (z == 0) ? Wq : (z == 1) ? Wk : (z == 2) ? Wv : Wo;
    short* dst = (z == 3) ? WoT : WcatT + (size_t)z * 1024 * 1024;
    int tx = threadIdx.x & 31, ty = threadIdx.x >> 5;  // 32 x 8
    int kk0 = bx * 32;   // src rows (k)
    int nn0 = by * 32;   // src cols (n)
#pragma unroll
    for (int j = 0; j < 4; j++)
      tl[ty + j * 8][tx] = src[(size_t)(kk0 + ty + j * 8) * 1024 + nn0 + tx];
    __syncthreads();
#pragma unroll
    for (int j = 0; j < 4; j++)
      dst[(size_t)(nn0 + ty + j * 8) * 1024 + kk0 + tx] = f2bf(tl[tx][ty + j * 8]);
  }
}

// gather-reduce over 32-row chunk partials, XCD-pinned slot map (round 6).
// chunk (c, j): k-groups {2c, 2c+1} (full, j >= 4c+2) or {2c} (single,
// j in {4c, 4c+1}).  Forward map (see attn_kernel): XCD x = b&7, s = b>>3;
//   full c=x:    slot = c + 8*(j - 4c - 2)
//   full c>=8:   slot = (15-c) + 8*j
//   single c<=7: slot = c + 8*(64 + (j&3))
//   single c>=8: slot = (15-c) + 8*(66 + (j&3))
__global__ __launch_bounds__(256) void reduce_y(const short* __restrict__ Ypc,
                                                const float* __restrict__ Cvs,
                                                short* __restrict__ o) {
  int q = blockIdx.x;
  int j = q >> 5, qr = q & 31;
  int col = threadIdx.x * 4;
  float a0 = Cvs[col + 0], a1 = Cvs[col + 1], a2 = Cvs[col + 2], a3 = Cvs[col + 3];
  int cf = (j - 2) >> 2;                       // last full chunk (may be -1)
  for (int c = 0; c <= cf; c++) {
    int slot = (c <= 7) ? (c + 8 * (j - 4 * c - 2)) : ((15 - c) + 8 * j);
    const short* p = Ypc + ((size_t)slot * 32 + qr) * 1024 + col;
    short4v v = *(const short4v*)p;
    a0 += bf2f(v[0]); a1 += bf2f(v[1]); a2 += bf2f(v[2]); a3 += bf2f(v[3]);
  }
  if ((j & 3) < 2) {                           // diagonal single-group chunk
    int cp = j >> 2;
    int slot = (cp <= 7) ? (cp + 8 * (64 + (j & 3)))
                         : ((15 - cp) + 8 * (66 + (j & 3)));
    const short* p = Ypc + ((size_t)slot * 32 + qr) * 1024 + col;
    short4v v = *(const short4v*)p;
    a0 += bf2f(v[0]); a1 += bf2f(v[1]); a2 += bf2f(v[2]); a3 += bf2f(v[3]);
  }
  uint32_t u0 = cvt_pk_bf16(a0, a1), u1 = cvt_pk_bf16(a2, a3);
  short4v rr = { (short)u0, (short)(u0 >> 16), (short)u1, (short)(u1 >> 16) };
  *(short4v*)&o[(size_t)q * 1024 + col] = rr;
}

// V [h][k 2048][d 64] -> Vt [h][d 64][k 2048]; fused vsum: each block
// atomically accumulates (1/16)*sum over its 64 k of V[h][k][d] into Cvs.
// (r15 lesson: fusing this into gemm_qkv's epilogue scatters 8B stores at
// 4KB stride -> ~16x write amplification; the LDS-staged transpose here is
// the cheap correct way.)
__global__ __launch_bounds__(256) void transpose_v(const short* __restrict__ Vb,
                                                   short* __restrict__ Vt,
                                                   float* __restrict__ Cvs) {
  __shared__ short tv[64][72];
  int h = blockIdx.y, k0 = blockIdx.x * 64;
  int tid = threadIdx.x;
#pragma unroll
  for (int j = 0; j < 2; j++) {
    int idx = tid + j * 256;
    int row = idx >> 3, c = idx & 7;
    bf16x8 v = *(const bf16x8*)&Vb[((size_t)h * 2048 + k0 + row) * 64 + c * 8];
#pragma unroll
    for (int t = 0; t < 8; t++) tv[row][c * 8 + t] = v[t];
  }
  __syncthreads();
#pragma unroll
  for (int j = 0; j < 2; j++) {
    int idx = tid + j * 256;
    int d = idx >> 3, c = idx & 7;
    bf16x8 v;
#pragma unroll
    for (int t = 0; t < 8; t++) v[t] = tv[c * 8 + t][d];
    *(bf16x8*)&Vt[((size_t)h * 64 + d) * 2048 + k0 + c * 8] = v;
  }
  // fused vsum: column-sum of the staged tile (tv unchanged by phase 2)
  if (tid < 64) {
    float s = 0.f;
#pragma unroll 8
    for (int k = 0; k < 64; k++) s += bf2f(tv[k][tid]);
    atomicAdd(&Cvs[h * 64 + tid], s * 0.0625f);
  }
}

// ---------- QKV GEMM: [Q|K|V](+rope) = Xbf * WcatT^T; 64x96 tiles ----------
// 1-D grid 1024, XCD-chunked swizzle (T1): id = (b&7)*128 + (b>>3);
// ny = id>>5, mx = id&31.  Each XCD owns 4 contiguous n-tiles -> its 32x
// B-panel re-reads hit XCD-local L2 (768KB B + ~4MB A working set); default
// ordering replicated every B panel into all 8 L2s.  nwg%8==0 -> bijective.
// 4 blocks/CU; wave tile 32x48 (acc[2][3]); LDS 20KB; live ~80 VGPR.
__global__ __launch_bounds__(256, 4)
void gemm_qkv(const short* __restrict__ A, const short* __restrict__ B,
              short* __restrict__ Qb, short* __restrict__ Kb,
              short* __restrict__ Vb) {
  __shared__ __attribute__((aligned(16))) short lga[64 * 64];
  __shared__ __attribute__((aligned(16))) short lgb[96 * 64];
  const int tid = threadIdx.x;
  const int lane = tid & 63;
  const int w = tid >> 6;
  const int l15 = lane & 15;
  const int quad = lane >> 4;
  const int wm = w >> 1, wn = w & 1;
  const int bb = blockIdx.x;
  const int id = (bb & 7) * 128 + (bb >> 3);   // XCD-chunked remap
  const int m0 = (id & 31) * 64, n0 = (id >> 5) * 96;
  const int rsub = lane >> 3;
  const int cpos = lane & 7;

  f32x4 acc[2][3];
#pragma unroll
  for (int i = 0; i < 2; i++)
#pragma unroll
    for (int j = 0; j < 3; j++) acc[i][j] = (f32x4){0.f, 0.f, 0.f, 0.f};

  for (int kb = 0; kb < 1024; kb += 64) {
    __syncthreads();
    int kc = cpos ^ rsub;
#pragma unroll
    for (int j = 0; j < 2; j++) {
      int r = (w * 2 + j) * 8 + rsub;
      gload_lds16(A + (size_t)(m0 + r) * 1024 + kb + kc * 8, &lga[(w * 2 + j) * 512]);
    }
#pragma unroll
    for (int j = 0; j < 3; j++) {
      int r = (w * 3 + j) * 8 + rsub;
      gload_lds16(B + (size_t)(n0 + r) * 1024 + kb + kc * 8, &lgb[(w * 3 + j) * 512]);
    }
    __syncthreads();
#pragma unroll
    for (int kk = 0; kk < 2; kk++) {
      bf16x8 af[2], bfr[3];
#pragma unroll
      for (int t = 0; t < 2; t++) {
        int row = wm * 32 + t * 16 + l15;
        int pc = (kk * 4 + quad) ^ (row & 7);
        af[t] = *(const bf16x8*)&lga[row * 64 + pc * 8];
      }
#pragma unroll
      for (int t = 0; t < 3; t++) {
        int rowb = wn * 48 + t * 16 + l15;
        int pcb = (kk * 4 + quad) ^ (rowb & 7);
        bfr[t] = *(const bf16x8*)&lgb[rowb * 64 + pcb * 8];
      }
#pragma unroll
      for (int mt = 0; mt < 2; mt++)
#pragma unroll
        for (int nt = 0; nt < 3; nt++)
          acc[mt][nt] = __builtin_amdgcn_mfma_f32_16x16x32_bf16(
              af[mt], bfr[nt], acc[mt][nt], 0, 0, 0);
    }
  }

#pragma unroll
  for (int mt = 0; mt < 2; mt++) {
#pragma unroll
    for (int nt = 0; nt < 3; nt++) {
      int n = n0 + wn * 48 + nt * 16 + l15;
      int mat = n >> 10;
      int h = (n >> 6) & 15;
      int d = n & 63;
#pragma unroll
      for (int r = 0; r < 4; r++) {
        int q = m0 + wm * 32 + mt * 16 + quad * 4 + r;
        float v = acc[mt][nt][r];
        float o = __shfl_xor(v, 1, 64);
        if (mat < 2) {
          int i = d >> 1;
          float ang = (float)q * __builtin_exp2f(-(float)i * 0.2801807588956902f);
          float sn, cs;
          __sincosf(ang, &sn, &cs);
          float rv = (d & 1) ? (o * sn + v * cs) : (v * cs - o * sn);
          short* dst = (mat == 0) ? Qb : Kb;
          dst[((size_t)h * 2048 + q) * 64 + d] = f2bf(rv);
        } else {
          Vb[((size_t)h * 2048 + q) * 64 + d] = f2bf(v);
        }
      }
    }
  }
}

// ---------- output GEMM: out[2048x1024] = Ycbf * WoT^T; 64x64 tiles ----------
// 1-D grid 512, XCD-chunked swizzle: id = (b&7)*64 + (b>>3); ny = id>>5,
// mx = id&31.  2 n-tiles/XCD (256KB B + ~4MB A working set in L2).
// 2 independent blocks/CU (r13 win); wave tile 32x32; LDS 16KB.
__global__ __launch_bounds__(256, 4)
void gemm_o(const short* __restrict__ A, const short* __restrict__ B,
            float* __restrict__ C) {
  __shared__ __attribute__((aligned(16))) short lga[64 * 64];
  __shared__ __attribute__((aligned(16))) short lgb[64 * 64];
  const int tid = threadIdx.x;
  const int lane = tid & 63;
  const int w = tid >> 6;                      // 0..3
  const int l15 = lane & 15;
  const int quad = lane >> 4;
  const int wm = w >> 1, wn = w & 1;
  const int bb = blockIdx.x;
  const int id = (bb & 7) * 64 + (bb >> 3);    // XCD-chunked remap
  const int m0 = (id & 31) * 64, n0 = (id >> 5) * 64;
  const int rsub = lane >> 3;
  const int cpos = lane & 7;

  f32x4 acc[2][2];
#pragma unroll
  for (int i = 0; i < 2; i++)
#pragma unroll
    for (int j = 0; j < 2; j++) acc[i][j] = (f32x4){0.f, 0.f, 0.f, 0.f};

  for (int kb = 0; kb < 1024; kb += 64) {
    __syncthreads();
    int kc = cpos ^ rsub;
#pragma unroll
    for (int j = 0; j < 2; j++) {
      int r = (w * 2 + j) * 8 + rsub;
      gload_lds16(A + (size_t)(m0 + r) * 1024 + kb + kc * 8, &lga[(w * 2 + j) * 512]);
      gload_lds16(B + (size_t)(n0 + r) * 1024 + kb + kc * 8, &lgb[(w * 2 + j) * 512]);
    }
    __syncthreads();
#pragma unroll
    for (int kk = 0; kk < 2; kk++) {
      bf16x8 af[2], bfr[2];
#pragma unroll
      for (int t = 0; t < 2; t++) {
        int row = wm * 32 + t * 16 + l15;
        int pc = (kk * 4 + quad) ^ (row & 7);
        af[t] = *(const bf16x8*)&lga[row * 64 + pc * 8];
        int rowb = wn * 32 + t * 16 + l15;
        int pcb = (kk * 4 + quad) ^ (rowb & 7);
        bfr[t] = *(const bf16x8*)&lgb[rowb * 64 + pcb * 8];
      }
#pragma unroll
      for (int mt = 0; mt < 2; mt++)
#pragma unroll
        for (int nt = 0; nt < 2; nt++)
          acc[mt][nt] = __builtin_amdgcn_mfma_f32_16x16x32_bf16(
              af[mt], bfr[nt], acc[mt][nt], 0, 0, 0);
    }
  }

#pragma unroll
  for (int mt = 0; mt < 2; mt++) {
    int q = m0 + wm * 32 + mt * 16 + quad * 4;
#pragma unroll
    for (int nt = 0; nt < 2; nt++) {
      int n = n0 + wn * 32 + nt * 16 + l15;
#pragma unroll
      for (int r = 0; r < 4; r++) C[(size_t)(q + r) * 1024 + n] = acc[mt][nt][r];
    }
  }
}

// ---------- causal attention, head-axis softmax, A' = A - 1/16 ----------
// EXACT round-6/9/10 kernel (best measured: 68-70 us attn) -- FROZEN.
// 32-row q-tiles; XCD-pinned balanced chunk map; 1024 thr = 16 waves = 16
// heads; LDS 73728 -> 2 blocks/CU; (1024,2) -> VGPR cap 64, no spill.
// Q=32 geometry is the amortization optimum reachable under the 2048
// thread/CU limit (r11 lesson: Q=16 quadruples per-row K/V load cost).
__global__ __launch_bounds__(1024, 2)
void attn_kernel(const short* __restrict__ Qb, const short* __restrict__ Kb,
                 const short* __restrict__ Vt, short* __restrict__ Ypc) {
  __shared__ short Sb[16 * 32 * 72];   // [h][q 32][72: 64 k + pad], in-place
  const int tid = threadIdx.x;
  const int lane = tid & 63;
  const int h = tid >> 6;                    // wave = head, 0..15
  const int l15 = lane & 15, quad = lane >> 4;
  const int b = blockIdx.x;
  const int x = b & 7, s = b >> 3;
  int c, j, ng;
  const int n1 = 62 - 4 * x;                 // full chunks with c = x
  if (s < n1)      { c = x;      j = 4 * x + 2 + s;        ng = 2; }
  else if (s < 64) { c = 15 - x; j = s;                    ng = 2; }
  else if (s < 66) { c = x;      j = 4 * x + (s - 64);     ng = 1; }
  else             { c = 15 - x; j = 60 - 4 * x + (s - 66); ng = 1; }
  const int q0 = j * 32;
  const int g0 = 2 * c;

  bf16x8 qf[2][2];                           // [qsub][half-of-d]
#pragma unroll
  for (int qs = 0; qs < 2; qs++)
#pragma unroll
    for (int cc = 0; cc < 2; cc++)
      qf[qs][cc] = *(const bf16x8*)&Qb[((size_t)h * 2048 + q0 + qs * 16 + l15) * 64 +
                                       cc * 32 + quad * 8];

  f32x4 yacc[2][4];                          // [qsub][nt]
#pragma unroll
  for (int i = 0; i < 2; i++)
#pragma unroll
    for (int jj = 0; jj < 4; jj++) yacc[i][jj] = (f32x4){0.f, 0.f, 0.f, 0.f};

  for (int gi = 0; gi < ng; gi++) {
    const int k0 = (g0 + gi) * 64;
    // ---- S = (QK^T) * 0.125*log2e -> bf16 LDS [h][q 32][72] ----
#pragma unroll
    for (int st = 0; st < 4; st++) {
      const short* kb = &Kb[((size_t)h * 2048 + k0 + st * 16 + l15) * 64 + quad * 8];
      bf16x8 kf0 = *(const bf16x8*)kb;
      bf16x8 kf1 = *(const bf16x8*)(kb + 32);
#pragma unroll
      for (int qs = 0; qs < 2; qs++) {
        f32x4 sa = (f32x4){0.f, 0.f, 0.f, 0.f};
        sa = __builtin_amdgcn_mfma_f32_16x16x32_bf16(qf[qs][0], kf0, sa, 0, 0, 0);
        sa = __builtin_amdgcn_mfma_f32_16x16x32_bf16(qf[qs][1], kf1, sa, 0, 0, 0);
        const float cs = 0.18033688011112042f;   // 0.125 * log2(e)
        uint32_t u0 = cvt_pk_bf16(sa[0] * cs, sa[1] * cs);
        uint32_t u1 = cvt_pk_bf16(sa[2] * cs, sa[3] * cs);
        int rb = (h * 32 + qs * 16 + quad * 4) * 72 + st * 16 + l15;
        Sb[rb]       = (short)u0;
        Sb[rb + 72]  = (short)(u0 >> 16);
        Sb[rb + 144] = (short)u1;
        Sb[rb + 216] = (short)(u1 >> 16);
      }
    }
    __syncthreads();
    // ---- head-axis softmax IN PLACE (no max-sub); A' = softmax - 1/16 ----
    // 32q x 64k = 2048 positions, 1024 threads, 2 per thread (sequential).
#pragma unroll
    for (int pp = 0; pp < 2; pp++) {
      int p = tid + pp * 1024;
      int q = p >> 6, kl = p & 63;
      int base = q * 72 + kl;
      float t[16];
      float sum = 0.f;
#pragma unroll
      for (int hh = 0; hh < 16; hh++) {
        float e = __builtin_exp2f(bf2f(Sb[hh * 2304 + base]));
        t[hh] = e;
        sum += e;
      }
      bool msk = (k0 + kl) > (q0 + q);
      float rs = msk ? 0.f : 1.f / sum;
      float offv = msk ? 0.f : 0.0625f;
#pragma unroll
      for (int hh = 0; hh < 16; hh += 2) {
        uint32_t u = cvt_pk_bf16(t[hh] * rs - offv, t[hh + 1] * rs - offv);
        Sb[hh * 2304 + base]       = (short)u;
        Sb[(hh + 1) * 2304 + base] = (short)(u >> 16);
      }
    }
    __syncthreads();
    // ---- Y += A' @ V ---- (V frag per (kk,nt) loaded once, both qsubs)
#pragma unroll
    for (int kk = 0; kk < 2; kk++) {
      bf16x8 af0 = *(const bf16x8*)&Sb[(h * 32 + l15) * 72 + kk * 32 + quad * 8];
      bf16x8 af1 = *(const bf16x8*)&Sb[(h * 32 + 16 + l15) * 72 + kk * 32 + quad * 8];
#pragma unroll
      for (int nt = 0; nt < 4; nt++) {
        bf16x8 vf = *(const bf16x8*)&Vt[((size_t)h * 64 + nt * 16 + l15) * 2048 +
                                        k0 + kk * 32 + quad * 8];
        yacc[0][nt] = __builtin_amdgcn_mfma_f32_16x16x32_bf16(af0, vf, yacc[0][nt],
                                                              0, 0, 0);
        yacc[1][nt] = __builtin_amdgcn_mfma_f32_16x16x32_bf16(af1, vf, yacc[1][nt],
                                                              0, 0, 0);
      }
    }
    __syncthreads();
  }
  // write compact bf16 partial at chunk slot b: [32 q-rows][1024 cols]
  short* Y = Ypc + (size_t)b * 32 * 1024;
#pragma unroll
  for (int qs = 0; qs < 2; qs++) {
#pragma unroll
    for (int nt = 0; nt < 4; nt++) {
      int col = h * 64 + nt * 16 + l15;
#pragma unroll
      for (int rr = 0; rr < 4; rr++)
        Y[(size_t)(qs * 16 + quad * 4 + rr) * 1024 + col] = f2bf(yacc[qs][nt][rr]);
    }
  }
}

// ---------- host ----------
extern "C" void kernel_launch(void* const* d_in, const int* in_sizes, int n_in,
                              void* d_out, int out_size, void* d_ws, size_t ws_size,
                              hipStream_t stream) {
  (void)in_sizes; (void)n_in; (void)out_size; (void)ws_size;
  const float* X  = (const float*)d_in[0];
  const float* Wq = (const float*)d_in[2];
  const float* Wk = (const float*)d_in[3];
  const float* Wv = (const float*)d_in[4];
  const float* Wo = (const float*)d_in[5];
  char* ws = (char*)d_ws;
  const size_t MB = 1024 * 1024;
  short* Xbf   = (short*)(ws + 0);        // 4 MB; reused as Ycbf after gemm_qkv
  short* WcatT = (short*)(ws + 4 * MB);   // 6 MB [3072 n][1024 k]
  short* WoT   = (short*)(ws + 10 * MB);  // 2 MB [1024 n][1024 k]
  short* Qb    = (short*)(ws + 12 * MB);  // 4 MB [h][q][64]
  short* Kb    = (short*)(ws + 16 * MB);  // 4 MB [h][k][64]
  short* Vb    = (short*)(ws + 20 * MB);  // 4 MB [h][k][64]
  short* Vt    = (short*)(ws + 24 * MB);  // 4 MB [h][d][2048]
  short* Ypc   = (short*)(ws + 28 * MB);  // 34 MB: 544 chunk partials [32][1024]
  float* Cvs   = (float*)(ws + 63 * MB);  // 4 KB
  short* Ycbf  = Xbf;                     // alias (Xbf dead after gemm_qkv)
  float* out   = (float*)d_out;

  prep<<<dim3(6144), dim3(256), 0, stream>>>(X, Wq, Wk, Wv, Wo, Xbf, WcatT, WoT, Cvs);
  gemm_qkv<<<dim3(1024), dim3(256), 0, stream>>>(Xbf, WcatT, Qb, Kb, Vb);
  transpose_v<<<dim3(32, 16), dim3(256), 0, stream>>>(Vb, Vt, Cvs);
  attn_kernel<<<dim3(544), dim3(1024), 0, stream>>>(Qb, Kb, Vt, Ypc);
  reduce_y<<<dim3(2048), dim3(256), 0, stream>>>(Ypc, Cvs, Ycbf);
  gemm_o<<<dim3(512), dim3(256), 0, stream>>>(Ycbf, WoT, out);
}